// Round 1
// baseline (533.715 us; speedup 1.0000x reference)
//
#include <hip/hip_runtime.h>

// Problem: x (B=4, C=256, D=32, H=64, W=64) fp32.
// 1) reflect-pad(2) + per-(b,c) mean  == weighted sum over original x
// 2) LSTMCell scan over C=256 channels (B=4, hidden=32, input=1)
// 3) gate[b,c] = sigmoid(h_c . gate_w + gate_b);  out = x * gate[b,c]

#define CH_F4 32768          // 131072 floats per (b,c) channel = 32768 float4
#define NCH 1024             // B*C
#define MEAN_DEN (1.0f / 166464.0f)   // 36*68*68

__device__ __forceinline__ float sigf(float x) {
    return 1.0f / (1.0f + __expf(-x));
}
__device__ __forceinline__ float tanh_fast(float x) {
    // tanh(x) = 2*sigmoid(2x) - 1
    return fmaf(2.0f, sigf(2.0f * x), -1.0f);
}

// ---------- Kernel 1: weighted channel means (reflect-pad mean) ----------
__global__ __launch_bounds__(256) void mean_kernel(const float* __restrict__ x,
                                                   float* __restrict__ cseq) {
    const int bc = blockIdx.x;                       // 0..1023
    const float4* __restrict__ p = (const float4*)x + (size_t)bc * CH_F4;
    const int tid = threadIdx.x;

    float sum = 0.0f;
    for (int i = tid; i < CH_F4; i += 256) {
        float4 v = p[i];
        const int q = i & 15;            // float4 index within W-row (16 per row)
        const int h = (i >> 4) & 63;
        const int d = i >> 10;
        // W-dim weights: positions 1,2,61,62 doubled -> only q==0 and q==15 rows
        float t = (v.x + v.y) + (v.z + v.w);
        if (q == 0 || q == 15) t += v.y + v.z;
        // D-dim: {1,2,29,30} doubled; H-dim: {1,2,61,62} doubled
        const float wd = ((d == 1) | (d == 2) | (d == 29) | (d == 30)) ? 2.0f : 1.0f;
        const float wh = ((h == 1) | (h == 2) | (h == 61) | (h == 62)) ? 2.0f : 1.0f;
        sum = fmaf(wd * wh, t, sum);
    }

    __shared__ float red[256];
    red[tid] = sum;
    __syncthreads();
    for (int s = 128; s > 0; s >>= 1) {
        if (tid < s) red[tid] += red[tid + s];
        __syncthreads();
    }
    if (tid == 0) cseq[bc] = red[0] * MEAN_DEN;
}

// ---------- Kernel 2: LSTM scan over channels + output gate ----------
// One block, 512 threads: tid = b*128 + j, b in [0,4), j in [0,128) gate rows.
__global__ __launch_bounds__(512) void lstm_kernel(const float* __restrict__ cseq,
                                                   const float* __restrict__ W_ih,
                                                   const float* __restrict__ W_hh,
                                                   const float* __restrict__ b_ih,
                                                   const float* __restrict__ b_hh,
                                                   const float* __restrict__ gate_w,
                                                   const float* __restrict__ gate_b,
                                                   float* __restrict__ gates) {
    __shared__ float cs[1024];        // (B,C) channel means
    __shared__ float h_sh[4][32];
    __shared__ float z_sh[512];
    __shared__ float gp_sh[4][32];
    __shared__ float gw_sh[32];

    const int tid = threadIdx.x;
    const int b = tid >> 7;
    const int j = tid & 127;

    for (int i = tid; i < 1024; i += 512) cs[i] = cseq[i];
    if (tid < 32) gw_sh[tid] = gate_w[tid];
    if (j < 32) h_sh[b][j] = 0.0f;

    const float wih = W_ih[j];
    const float bias = b_ih[j] + b_hh[j];
    float whh[32];
#pragma unroll
    for (int k = 0; k < 32; k++) whh[k] = W_hh[j * 32 + k];
    float creg = 0.0f;
    const float gb = gate_b[0];
    __syncthreads();

    for (int t = 0; t < 256; t++) {
        const float inp = cs[b * 256 + t];
        // z[b][j] = inp*W_ih[j] + bias[j] + h[b,:] . W_hh[j,:]
        float z0 = fmaf(inp, wih, bias), z1 = 0.f, z2 = 0.f, z3 = 0.f;
#pragma unroll
        for (int k = 0; k < 32; k += 4) {
            z0 = fmaf(h_sh[b][k + 0], whh[k + 0], z0);
            z1 = fmaf(h_sh[b][k + 1], whh[k + 1], z1);
            z2 = fmaf(h_sh[b][k + 2], whh[k + 2], z2);
            z3 = fmaf(h_sh[b][k + 3], whh[k + 3], z3);
        }
        z_sh[tid] = (z0 + z1) + (z2 + z3);
        __syncthreads();

        if (j < 32) {
            const float zi = z_sh[b * 128 + j];
            const float zf = z_sh[b * 128 + 32 + j];
            const float zg = z_sh[b * 128 + 64 + j];
            const float zo = z_sh[b * 128 + 96 + j];
            creg = sigf(zf) * creg + sigf(zi) * tanh_fast(zg);
            const float hv = sigf(zo) * tanh_fast(creg);
            h_sh[b][j] = hv;
            gp_sh[b][j] = hv * gw_sh[j];
        }
        __syncthreads();

        if (j == 0) {
            float s = gb;
#pragma unroll
            for (int k = 0; k < 32; k++) s += gp_sh[b][k];
            gates[b * 256 + t] = sigf(s);
        }
    }
}

// ---------- Kernel 3: out = x * gate[b,c] ----------
// grid = (32, 1024); each block: 256 threads x 4 float4 = 4096 float4 chunk.
__global__ __launch_bounds__(256) void scale_kernel(const float* __restrict__ x,
                                                    const float* __restrict__ gates,
                                                    float* __restrict__ out) {
    const int bc = blockIdx.y;
    const float g = gates[bc];
    const size_t base = (size_t)bc * CH_F4;
    const float4* __restrict__ xi = (const float4*)x + base;
    float4* __restrict__ oi = (float4*)out + base;
    const int start = blockIdx.x * 1024 + threadIdx.x;
#pragma unroll
    for (int r = 0; r < 4; r++) {
        const int idx = start + r * 256;
        float4 v = xi[idx];
        v.x *= g; v.y *= g; v.z *= g; v.w *= g;
        oi[idx] = v;
    }
}

extern "C" void kernel_launch(void* const* d_in, const int* in_sizes, int n_in,
                              void* d_out, int out_size, void* d_ws, size_t ws_size,
                              hipStream_t stream) {
    const float* x      = (const float*)d_in[0];
    const float* W_ih   = (const float*)d_in[1];   // (128,1)
    const float* W_hh   = (const float*)d_in[2];   // (128,32)
    const float* b_ih   = (const float*)d_in[3];   // (128,)
    const float* b_hh   = (const float*)d_in[4];   // (128,)
    const float* gate_w = (const float*)d_in[5];   // (1,32)
    const float* gate_b = (const float*)d_in[6];   // (1,)
    float* out = (float*)d_out;

    float* cseq  = (float*)d_ws;          // 1024 floats
    float* gates = (float*)d_ws + 1024;   // 1024 floats

    mean_kernel<<<NCH, 256, 0, stream>>>(x, cseq);
    lstm_kernel<<<1, 512, 0, stream>>>(cseq, W_ih, W_hh, b_ih, b_hh,
                                       gate_w, gate_b, gates);
    scale_kernel<<<dim3(32, NCH), 256, 0, stream>>>(x, gates, out);
}

// Round 2
// 417.143 us; speedup vs baseline: 1.2795x; 1.2795x over previous
//
#include <hip/hip_runtime.h>

// Problem: x (B=4, C=256, D=32, H=64, W=64) fp32.
// 1) reflect-pad(2) + per-(b,c) mean  == weighted sum over original x
// 2) LSTMCell scan over C=256 channels (B=4, hidden=32, input=1)
// 3) gate[b,c] = sigmoid(h_c . gate_w + gate_b);  out = x * gate[b,c]

#define CH_F4 32768          // 131072 floats per (b,c) channel = 32768 float4
#define NCH 1024             // B*C
#define MEAN_DEN (1.0f / 166464.0f)   // 36*68*68

__device__ __forceinline__ float sigf(float x) {
    return 1.0f / (1.0f + __expf(-x));
}
__device__ __forceinline__ float tanh_fast(float x) {
    // tanh(x) = 2*sigmoid(2x) - 1
    return fmaf(2.0f, sigf(2.0f * x), -1.0f);
}

// ---------- Kernel 1: weighted channel means (reflect-pad mean) ----------
__global__ __launch_bounds__(256) void mean_kernel(const float* __restrict__ x,
                                                   float* __restrict__ cseq) {
    const int bc = blockIdx.x;                       // 0..1023
    const float4* __restrict__ p = (const float4*)x + (size_t)bc * CH_F4;
    const int tid = threadIdx.x;

    float sum = 0.0f;
    for (int i = tid; i < CH_F4; i += 256) {
        float4 v = p[i];
        const int q = i & 15;            // float4 index within W-row (16 per row)
        const int h = (i >> 4) & 63;
        const int d = i >> 10;
        // W-dim weights: positions 1,2,61,62 doubled -> only q==0 and q==15 rows
        float t = (v.x + v.y) + (v.z + v.w);
        if (q == 0 || q == 15) t += v.y + v.z;
        // D-dim: {1,2,29,30} doubled; H-dim: {1,2,61,62} doubled
        const float wd = ((d == 1) | (d == 2) | (d == 29) | (d == 30)) ? 2.0f : 1.0f;
        const float wh = ((h == 1) | (h == 2) | (h == 61) | (h == 62)) ? 2.0f : 1.0f;
        sum = fmaf(wd * wh, t, sum);
    }

    __shared__ float red[256];
    red[tid] = sum;
    __syncthreads();
    for (int s = 128; s > 0; s >>= 1) {
        if (tid < s) red[tid] += red[tid + s];
        __syncthreads();
    }
    if (tid == 0) cseq[bc] = red[0] * MEAN_DEN;
}

// ---------- Kernel 2: LSTM scan, 4 independent single-wave blocks ----------
// Block b (of 4), 64 lanes. Lane l owns gate rows l and l+64:
//   l<32 : rows l (i_l)      and l+64 (g_l)
//   l>=32: rows l (f_{l-32}) and l+64 (o_{l-32})
// h-broadcast via LDS; i/f <-> g/o recombined with __shfl_xor(.,32).
// Output-gate dot products deferred: h history kept in padded LDS, gates
// computed in parallel after the scan (no per-step reduce on critical path).
__global__ __launch_bounds__(64) void lstm_kernel(const float* __restrict__ cseq,
                                                  const float* __restrict__ W_ih,
                                                  const float* __restrict__ W_hh,
                                                  const float* __restrict__ b_ih,
                                                  const float* __restrict__ b_hh,
                                                  const float* __restrict__ gate_w,
                                                  const float* __restrict__ gate_b,
                                                  float* __restrict__ gates) {
    __shared__ float cs[256];
    __shared__ float hist[256 * 33 + 32];   // h history, row stride 33 (bank-conflict-free)

    const int b = blockIdx.x;    // 0..3
    const int l = threadIdx.x;   // 0..63
    const int r0 = l, r1 = l + 64;

    const float wih0 = W_ih[r0];
    const float wih1 = W_ih[r1];
    const float bias0 = b_ih[r0] + b_hh[r0];
    const float bias1 = b_ih[r1] + b_hh[r1];
    float whh0[32], whh1[32];
#pragma unroll
    for (int k = 0; k < 32; k++) {
        whh0[k] = W_hh[r0 * 32 + k];
        whh1[k] = W_hh[r1 * 32 + k];
    }
#pragma unroll
    for (int i = 0; i < 4; i++) cs[l * 4 + i] = cseq[b * 256 + l * 4 + i];
    if (l < 32) hist[l] = 0.0f;   // t=-1 state slot reused as hist row of t=0 input
    float c = 0.0f;
    __syncthreads();

    // hist row t holds h AFTER step t, at hist[(t+1)*33 ... ]; row 0 = zeros.
    for (int t = 0; t < 256; t++) {
        const float inp = cs[t];
        const float* hrow = &hist[t * 33];
        float z0 = fmaf(inp, wih0, bias0);
        float z1 = fmaf(inp, wih1, bias1);
#pragma unroll
        for (int k = 0; k < 32; k++) {
            const float hk = hrow[k];
            z0 = fmaf(hk, whh0[k], z0);
            z1 = fmaf(hk, whh1[k], z1);
        }
        // recombine: lane l<32 needs zf,zo from lane l+32
        const float zf = __shfl_xor(z0, 32);
        const float zo = __shfl_xor(z1, 32);
        // lanes >=32 compute finite garbage (never stored)
        c = sigf(zf) * c + sigf(z0) * tanh_fast(z1);
        const float hv = sigf(zo) * tanh_fast(c);
        if (l < 32) hist[(t + 1) * 33 + l] = hv;
        __syncthreads();
    }

    // deferred output gates: lane handles t = l, l+64, l+128, l+192
    float gw[32];
#pragma unroll
    for (int k = 0; k < 32; k++) gw[k] = gate_w[k];
    const float gb = gate_b[0];
#pragma unroll
    for (int chunk = 0; chunk < 4; chunk++) {
        const int t = chunk * 64 + l;
        const float* hrow = &hist[(t + 1) * 33];   // h after step t
        float s = gb;
#pragma unroll
        for (int k = 0; k < 32; k++) s = fmaf(hrow[k], gw[k], s);
        gates[b * 256 + t] = sigf(s);
    }
}

// ---------- Kernel 3: out = x * gate[b,c], reverse channel order ----------
// Reverse order so the tail of x (still L3-resident from the mean pass)
// is read first -> partial second-read L3 hits.
__global__ __launch_bounds__(256) void scale_kernel(const float* __restrict__ x,
                                                    const float* __restrict__ gates,
                                                    float* __restrict__ out) {
    const int bc = (NCH - 1) - blockIdx.y;
    const float g = gates[bc];
    const size_t base = (size_t)bc * CH_F4;
    const float4* __restrict__ xi = (const float4*)x + base;
    float4* __restrict__ oi = (float4*)out + base;
    const int start = blockIdx.x * 1024 + threadIdx.x;
#pragma unroll
    for (int r = 0; r < 4; r++) {
        const int idx = start + r * 256;
        float4 v = xi[idx];
        v.x *= g; v.y *= g; v.z *= g; v.w *= g;
        oi[idx] = v;
    }
}

extern "C" void kernel_launch(void* const* d_in, const int* in_sizes, int n_in,
                              void* d_out, int out_size, void* d_ws, size_t ws_size,
                              hipStream_t stream) {
    const float* x      = (const float*)d_in[0];
    const float* W_ih   = (const float*)d_in[1];   // (128,1)
    const float* W_hh   = (const float*)d_in[2];   // (128,32)
    const float* b_ih   = (const float*)d_in[3];   // (128,)
    const float* b_hh   = (const float*)d_in[4];   // (128,)
    const float* gate_w = (const float*)d_in[5];   // (1,32)
    const float* gate_b = (const float*)d_in[6];   // (1,)
    float* out = (float*)d_out;

    float* cseq  = (float*)d_ws;          // 1024 floats
    float* gates = (float*)d_ws + 1024;   // 1024 floats

    mean_kernel<<<NCH, 256, 0, stream>>>(x, cseq);
    lstm_kernel<<<4, 64, 0, stream>>>(cseq, W_ih, W_hh, b_ih, b_hh,
                                      gate_w, gate_b, gates);
    scale_kernel<<<dim3(32, NCH), 256, 0, stream>>>(x, gates, out);
}

// Round 4
// 406.097 us; speedup vs baseline: 1.3143x; 1.0272x over previous
//
#include <hip/hip_runtime.h>

// Problem: x (B=4, C=256, D=32, H=64, W=64) fp32.
// 1) reflect-pad(2) + per-(b,c) mean  == weighted sum over original x
// 2) LSTMCell scan over C=256 channels (B=4, hidden=32, input=1)
// 3) gate[b,c] = sigmoid(h_c . gate_w + gate_b);  out = x * gate[b,c]

#define CH_F4 32768          // 131072 floats per (b,c) channel = 32768 float4
#define NCH 1024             // B*C
#define MEAN_DEN (1.0f / 166464.0f)   // 36*68*68

typedef unsigned int uint;
typedef float f32x4 __attribute__((ext_vector_type(4)));  // native vector: OK for nontemporal builtins

__device__ __forceinline__ float sigf(float x) {
    return 1.0f / (1.0f + __expf(-x));
}
__device__ __forceinline__ float tanh_fast(float x) {
    // tanh(x) = 2*sigmoid(2x) - 1
    return fmaf(2.0f, sigf(2.0f * x), -1.0f);
}

// ---------- Kernel 1: weighted channel means (reflect-pad mean) ----------
__global__ __launch_bounds__(256) void mean_kernel(const float* __restrict__ x,
                                                   float* __restrict__ cseq) {
    const int bc = blockIdx.x;                       // 0..1023
    const f32x4* __restrict__ p = (const f32x4*)x + (size_t)bc * CH_F4;
    const int tid = threadIdx.x;

    float sum = 0.0f;
    for (int i = tid; i < CH_F4; i += 256) {
        f32x4 v = p[i];
        const int q = i & 15;            // float4 index within W-row (16 per row)
        const int h = (i >> 4) & 63;
        const int d = i >> 10;
        // W-dim weights: positions 1,2,61,62 doubled -> only q==0 and q==15 rows
        float t = (v.x + v.y) + (v.z + v.w);
        if (q == 0 || q == 15) t += v.y + v.z;
        // D-dim: {1,2,29,30} doubled; H-dim: {1,2,61,62} doubled
        const float wd = ((d == 1) | (d == 2) | (d == 29) | (d == 30)) ? 2.0f : 1.0f;
        const float wh = ((h == 1) | (h == 2) | (h == 61) | (h == 62)) ? 2.0f : 1.0f;
        sum = fmaf(wd * wh, t, sum);
    }

    __shared__ float red[256];
    red[tid] = sum;
    __syncthreads();
    for (int s = 128; s > 0; s >>= 1) {
        if (tid < s) red[tid] += red[tid + s];
        __syncthreads();
    }
    if (tid == 0) cseq[bc] = red[0] * MEAN_DEN;
}

// ---------- Kernel 2: LSTM scan, 4 single-wave blocks, register-resident h ----------
// Block b, 64 lanes. Lane l owns gate rows l and l+64:
//   l<32 : rows l (i_l)      and l+64 (g_l)
//   l>=32: rows l (f_{l-32}) and l+64 (o_{l-32})
// h lives in ONE register (lane k holds h_k, k<32). The h-broadcast for the
// matvec is 32 v_readlane -> SGPR, consumed as the scalar FMA operand: no LDS,
// no barrier, no shfl on the recurrence. i/f <-> g/o recombination via
// v_permlane32_swap (VALU, not LDS pipe). h history is written to LDS purely
// for the deferred (post-scan, parallel) output-gate dot products.
__global__ __launch_bounds__(64) void lstm_kernel(const float* __restrict__ cseq,
                                                  const float* __restrict__ W_ih,
                                                  const float* __restrict__ W_hh,
                                                  const float* __restrict__ b_ih,
                                                  const float* __restrict__ b_hh,
                                                  const float* __restrict__ gate_w,
                                                  const float* __restrict__ gate_b,
                                                  float* __restrict__ gates) {
    __shared__ float cs[256];
    __shared__ float hist[257 * 33];   // row stride 33: conflict-free epilogue reads

    const int b = blockIdx.x;    // 0..3
    const int l = threadIdx.x;   // 0..63
    const int r0 = l, r1 = l + 64;

    const float wih0 = W_ih[r0];
    const float wih1 = W_ih[r1];
    const float bias0 = b_ih[r0] + b_hh[r0];
    const float bias1 = b_ih[r1] + b_hh[r1];
    float whh0[32], whh1[32];
#pragma unroll
    for (int k = 0; k < 32; k++) {
        whh0[k] = W_hh[r0 * 32 + k];
        whh1[k] = W_hh[r1 * 32 + k];
    }
#pragma unroll
    for (int i = 0; i < 4; i++) cs[i * 64 + l] = cseq[b * 256 + i * 64 + l];
    float h = 0.0f;   // lane k holds h_k (k<32); high lanes hold don't-care
    float c = 0.0f;
    __syncthreads();

    for (int t = 0; t < 256; t++) {
        const float inp = cs[t];
        float z0 = fmaf(inp, wih0, bias0);
        float z1 = fmaf(inp, wih1, bias1);
#pragma unroll
        for (int k = 0; k < 32; k++) {
            const float hk = __builtin_bit_cast(float,
                __builtin_amdgcn_readlane(__builtin_bit_cast(int, h), k));
            z0 = fmaf(hk, whh0[k], z0);
            z1 = fmaf(hk, whh1[k], z1);
        }
        // lanes<32 need z0,z1 of lane+32 (zf, zo). permlane32_swap: result[1]'s
        // low 32 lanes = source's high 32 lanes. High lanes get garbage - unused.
        float zf, zo;
#if __has_builtin(__builtin_amdgcn_permlane32_swap)
        {
            auto ra = __builtin_amdgcn_permlane32_swap(
                __builtin_bit_cast(uint, z0), __builtin_bit_cast(uint, z0), false, false);
            auto rb = __builtin_amdgcn_permlane32_swap(
                __builtin_bit_cast(uint, z1), __builtin_bit_cast(uint, z1), false, false);
            zf = __builtin_bit_cast(float, ra[1]);
            zo = __builtin_bit_cast(float, rb[1]);
        }
#else
        zf = __shfl_xor(z0, 32);
        zo = __shfl_xor(z1, 32);
#endif
        // valid in lanes<32 only (high lanes compute finite garbage, never read)
        c = sigf(zf) * c + sigf(z0) * tanh_fast(z1);
        h = sigf(zo) * tanh_fast(c);
        if (l < 32) hist[(t + 1) * 33 + l] = h;   // off critical path, no barrier
    }
    __syncthreads();

    // deferred output gates: lane handles t = l, l+64, l+128, l+192
    float gw[32];
#pragma unroll
    for (int k = 0; k < 32; k++) gw[k] = gate_w[k];
    const float gb = gate_b[0];
#pragma unroll
    for (int chunk = 0; chunk < 4; chunk++) {
        const int t = chunk * 64 + l;
        const float* hrow = &hist[(t + 1) * 33];   // h after step t
        float s = gb;
#pragma unroll
        for (int k = 0; k < 32; k++) s = fmaf(hrow[k], gw[k], s);
        gates[b * 256 + t] = sigf(s);
    }
}

// ---------- Kernel 3: out = x * gate[b,c], reverse channel order ----------
// Reverse order so the tail of x (still L3-resident from the mean pass) is
// read first. Nontemporal stores: the write stream has no reuse - don't let
// it evict x from L3.
__global__ __launch_bounds__(256) void scale_kernel(const float* __restrict__ x,
                                                    const float* __restrict__ gates,
                                                    float* __restrict__ out) {
    const int bc = (NCH - 1) - blockIdx.y;
    const float g = gates[bc];
    const size_t base = (size_t)bc * CH_F4;
    const f32x4* __restrict__ xi = (const f32x4*)x + base;
    f32x4* __restrict__ oi = (f32x4*)out + base;
    const int start = blockIdx.x * 1024 + threadIdx.x;
#pragma unroll
    for (int r = 0; r < 4; r++) {
        const int idx = start + r * 256;
        f32x4 v = xi[idx];
        v *= g;
        __builtin_nontemporal_store(v, &oi[idx]);
    }
}

extern "C" void kernel_launch(void* const* d_in, const int* in_sizes, int n_in,
                              void* d_out, int out_size, void* d_ws, size_t ws_size,
                              hipStream_t stream) {
    const float* x      = (const float*)d_in[0];
    const float* W_ih   = (const float*)d_in[1];   // (128,1)
    const float* W_hh   = (const float*)d_in[2];   // (128,32)
    const float* b_ih   = (const float*)d_in[3];   // (128,)
    const float* b_hh   = (const float*)d_in[4];   // (128,)
    const float* gate_w = (const float*)d_in[5];   // (1,32)
    const float* gate_b = (const float*)d_in[6];   // (1,)
    float* out = (float*)d_out;

    float* cseq  = (float*)d_ws;          // 1024 floats
    float* gates = (float*)d_ws + 1024;   // 1024 floats

    mean_kernel<<<NCH, 256, 0, stream>>>(x, cseq);
    lstm_kernel<<<4, 64, 0, stream>>>(cseq, W_ih, W_hh, b_ih, b_hh,
                                      gate_w, gate_b, gates);
    scale_kernel<<<dim3(32, NCH), 256, 0, stream>>>(x, gates, out);
}